// Round 8
// baseline (240.202 us; speedup 1.0000x reference)
//
#include <hip/hip_runtime.h>
#include <hip/hip_bf16.h>

typedef unsigned int u32;
typedef unsigned short u16;
typedef unsigned char u8;
typedef __attribute__((ext_vector_type(4))) float f32x4;
typedef __attribute__((ext_vector_type(2))) float f32x2;
typedef __attribute__((ext_vector_type(2))) long i64x2;

#define N_NODES 100000
#define N_EDGES 50000
#define D0      128
#define MPAD    100096
#define HIDN    256
#define NC      40

__device__ __forceinline__ float b2f(u32 h) { return __uint_as_float(h << 16); }
__device__ __forceinline__ u16 f2b(float f) {
  u32 u = __float_as_uint(f);
  u32 r = (u + 0x7fffu + ((u >> 16) & 1u)) >> 16;
  return (u16)r;
}
// byte-offset field swap within a 128B row: bits [6:5] <-> [4:3] (involution)
__device__ __forceinline__ int swapf(int o) {
  return ((o >> 2) & 0x18) | ((o << 2) & 0x60) | (o & 7);
}

// ---- fused prep ---------------------------------------------------------
// blocks [0,12500): node_x f32 -> x0f fp8 (perm rows)
// blocks [12500,12536): zero pad rows of x0f/nx1f/nx2f
// blocks [12536,12792): W1 -> W1F fp8 N-major folded, x64 scale, perm per 128B chunk
// blocks [12792,12840): W2 -> W2T bf16 N-major padded
__global__ __launch_bounds__(256) void k_prep(const float* __restrict__ node_x,
                                              const float* __restrict__ W1,
                                              const float* __restrict__ W2,
                                              u8* __restrict__ x0f, u8* __restrict__ nx1f,
                                              u8* __restrict__ nx2f, u8* __restrict__ W1F,
                                              u16* __restrict__ W2T) {
  const int blk = blockIdx.x;
  const int tid = threadIdx.x;
  if (blk < 12500) {
    int t = blk * 256 + tid;                      // one u32 (4 fp8) each
    int row = t >> 5;
    int o = (t & 31) * 4;                         // dest byte offset (perm space)
    int p = swapf(o);                             // src col (o&3==0 -> p%4==0)
    const float4 v = *(const float4*)(node_x + (size_t)row * 128 + p);
    int w = __builtin_amdgcn_cvt_pk_fp8_f32(v.x, v.y, 0, false);
    w = __builtin_amdgcn_cvt_pk_fp8_f32(v.z, v.w, w, true);
    *(u32*)(x0f + (size_t)row * 128 + o) = (u32)w;
  } else if (blk < 12536) {
    int t = (blk - 12500) * 256 + tid;            // 9216 u32 zeros
    const size_t PO = (size_t)N_NODES * 128;
    u32* dst;
    if (t < 3072)      dst = (u32*)(x0f + PO) + t;
    else if (t < 6144) dst = (u32*)(nx1f + PO) + (t - 3072);
    else               dst = (u32*)(nx2f + PO) + (t - 6144);
    *dst = 0;
  } else if (blk < 12792) {
    int n = blk - 12536;
    if (tid < 192) {
      int d0 = 2 * tid;                           // dest k (0..383), even
      int c = d0 >> 7, od = d0 & 127;
      int ks = (c << 7) | swapf(od);              // src k (consecutive pair)
      float v[2];
#pragma unroll
      for (int j = 0; j < 2; ++j) {
        int k = ks + j;
        if (k < 128)      v[j] = W1[k * 256 + n];
        else if (k < 256) v[j] = W1[k * 256 + n] + W1[(k + 128) * 256 + n];
        else              v[j] = W1[(k + 128) * 256 + n];
      }
      int w = __builtin_amdgcn_cvt_pk_fp8_f32(v[0] * 64.f, v[1] * 64.f, 0, false);
      *(u16*)(W1F + (size_t)n * 384 + d0) = (u16)w;
    }
  } else {
    int t = (blk - 12792) * 256 + tid;            // 48*256
    int n = t >> 8, k = t & 255;
    W2T[t] = (n < NC) ? f2b(W2[k * NC + n]) : (u16)0;
  }
}

// ---- gather / segment-mean: wave per segment, scalar indices ------------
// seg id broadcast via readfirstlane -> map reads become s_load_dwordx16/x8;
// row loads are SGPR-base + lane*2 (1 coalesced 128B line per row).
template<int DEG>
__global__ __launch_bounds__(256) void k_gatherf(const u8* __restrict__ src,
                                                 const int* __restrict__ map,
                                                 u8* __restrict__ dst) {
  const int seg = __builtin_amdgcn_readfirstlane((blockIdx.x * 256 + threadIdx.x) >> 6);
  const int lane = threadIdx.x & 63;
  float a0 = 0.f, a1 = 0.f;
#pragma unroll
  for (int r = 0; r < DEG; ++r) {
    int idx = map[seg * DEG + r];                 // wave-uniform -> scalar load
    u16 h = *(const u16*)(src + (size_t)idx * 128 + lane * 2);
    f32x2 v = __builtin_amdgcn_cvt_pk_f32_fp8((int)h, false);
    a0 += v[0]; a1 += v[1];
  }
  const float s = 1.f / DEG;
  int w = __builtin_amdgcn_cvt_pk_fp8_f32(fmaxf(a0 * s, 0.f), fmaxf(a1 * s, 0.f), 0, false);
  *(u16*)(dst + (size_t)seg * 128 + lane * 2) = (u16)w;
}

// ---- fused head: [x0|nx1|nx2](100096x384 fp8, perm rows) @ W1F -> relu -> @W2 -> lsm
// GEMM1 reads A/B fragments DIRECTLY from global (L2/L3-hot; A just written by
// gathers, W1F 98KB). No LDS staging, no main-loop barriers. LDS = Hs only.
__global__ __launch_bounds__(256) void k_head(const u8* __restrict__ x0f,
                                              const u8* __restrict__ nx1f,
                                              const u8* __restrict__ nx2f,
                                              const u8* __restrict__ W1F,
                                              const float* __restrict__ b1,
                                              const u16* __restrict__ W2T,
                                              const float* __restrict__ b2,
                                              float* __restrict__ out) {
  __shared__ u16 Hs[64 * 256];                      // 32KB
  const int tid = threadIdx.x;
  const int lane = tid & 63;
  const int wid = tid >> 6;                         // wave = output column block
  const int m0 = blockIdx.x * 64;
  const int q = lane >> 4;                          // K quarter

  f32x4 acc[4][4] = {};

#pragma unroll
  for (int ks = 0; ks < 3; ++ks) {
    const u8* Ap = (ks == 0) ? x0f : (ks == 1) ? nx1f : nx2f;
#pragma unroll
    for (int h = 0; h < 2; ++h) {                   // kk-pair per 16B read
      long a0[4], a1[4], b0[4], b1[4];
#pragma unroll
      for (int m = 0; m < 4; ++m) {
        int r = m0 + m * 16 + (lane & 15);
        i64x2 t = *(const i64x2*)(Ap + (size_t)r * 128 + q * 32 + h * 16);
        a0[m] = t[0]; a1[m] = t[1];
      }
#pragma unroll
      for (int n = 0; n < 4; ++n) {
        int r = wid * 64 + n * 16 + (lane & 15);
        i64x2 t = *(const i64x2*)(W1F + (size_t)r * 384 + ks * 128 + q * 32 + h * 16);
        b0[n] = t[0]; b1[n] = t[1];
      }
#pragma unroll
      for (int m = 0; m < 4; ++m)
#pragma unroll
        for (int n = 0; n < 4; ++n) {
          acc[m][n] = __builtin_amdgcn_mfma_f32_16x16x32_fp8_fp8(a0[m], b0[n], acc[m][n], 0, 0, 0);
          acc[m][n] = __builtin_amdgcn_mfma_f32_16x16x32_fp8_fp8(a1[m], b1[n], acc[m][n], 0, 0, 0);
        }
    }
  }

  const int rb = (lane >> 4) * 4, cb = lane & 15;
#pragma unroll
  for (int n = 0; n < 4; ++n) {                     // H = relu(acc/64 + b1) -> Hs (swizzled)
    int col = wid * 64 + n * 16 + cb;
    float bv = b1[col];
#pragma unroll
    for (int m = 0; m < 4; ++m) {
#pragma unroll
      for (int v = 0; v < 4; ++v) {
        int r = m * 16 + rb + v;
        u32 byo = ((u32)(r << 9) + (u32)(col << 1)) ^ (u32)((r & 7) << 4);
        *(u16*)((char*)Hs + byo) = f2b(fmaxf(acc[m][n][v] * 0.015625f + bv, 0.f));
      }
    }
  }
  __syncthreads();

  // GEMM2: each wave 16 rows; K=256; N=48 (3 frags); W2 from L2-hot global
  typedef __attribute__((ext_vector_type(8))) short bf16x8;
  f32x4 acc2[3] = {};
  const int r0g = wid * 16;
#pragma unroll
  for (int kk = 0; kk < 8; ++kk) {
    int arow = r0g + (lane & 15);
    int kb = (kk * 64 + ((lane >> 4) * 16)) ^ ((arow & 7) << 4);
    bf16x8 a = *(const bf16x8*)((const char*)Hs + arow * 512 + kb);
#pragma unroll
    for (int n = 0; n < 3; ++n) {
      int brow = n * 16 + (lane & 15);
      bf16x8 b = *(const bf16x8*)(W2T + brow * 256 + kk * 32 + (lane >> 4) * 8);
      acc2[n] = __builtin_amdgcn_mfma_f32_16x16x32_bf16(a, b, acc2[n], 0, 0, 0);
    }
  }

  float bias[3];
#pragma unroll
  for (int n = 0; n < 3; ++n) {
    int c2 = n * 16 + cb;
    bias[n] = (c2 < NC) ? b2[c2] : 0.f;
  }
#pragma unroll
  for (int v = 0; v < 4; ++v) {
    float z[3];
    float mx = -1e30f;
#pragma unroll
    for (int n = 0; n < 3; ++n) {
      int c2 = n * 16 + cb;
      z[n] = (c2 < NC) ? (acc2[n][v] + bias[n]) : -1e30f;
      mx = fmaxf(mx, z[n]);
    }
#pragma unroll
    for (int o = 1; o < 16; o <<= 1) mx = fmaxf(mx, __shfl_xor(mx, o));
    float s = 0.f;
#pragma unroll
    for (int n = 0; n < 3; ++n) {
      int c2 = n * 16 + cb;
      if (c2 < NC) s += expf(z[n] - mx);
    }
#pragma unroll
    for (int o = 1; o < 16; o <<= 1) s += __shfl_xor(s, o);
    float lse = logf(s);
    int grow = m0 + r0g + rb + v;
    if (grow < N_NODES) {
#pragma unroll
      for (int n = 0; n < 3; ++n) {
        int c2 = n * 16 + cb;
        if (c2 < NC) out[(size_t)grow * NC + c2] = z[n] - mx - lse;
      }
    }
  }
}

// ---- launch -------------------------------------------------------------

extern "C" void kernel_launch(void* const* d_in, const int* in_sizes, int n_in,
                              void* d_out, int out_size, void* d_ws, size_t ws_size,
                              hipStream_t stream) {
  const float* node_x    = (const float*)d_in[0];
  const int*   nodes_map = (const int*)d_in[1];
  const int*   edges_map = (const int*)d_in[3];
  const float* W1        = (const float*)d_in[5];
  const float* b1        = (const float*)d_in[6];
  const float* W2        = (const float*)d_in[7];
  const float* b2        = (const float*)d_in[8];
  float* out = (float*)d_out;
  char* ws = (char*)d_ws;

  u8*  x0f  = (u8*)(ws + 0);                        // 100096*128 = 12,812,288
  u8*  nx1f = (u8*)(ws + 12812288);
  u8*  nx2f = (u8*)(ws + 25624576);
  u8*  E1f  = (u8*)(ws + 38436864);                 // 50000*128 = 6,400,000
  u8*  E2f  = (u8*)(ws + 44836864);
  u8*  W1F  = (u8*)(ws + 51236864);                 // 256*384
  u16* W2T  = (u16*)(ws + 51335168);                // 48*256*2

  k_prep<<<12840, 256, 0, stream>>>(node_x, W1, W2, x0f, nx1f, nx2f, W1F, W2T);

  k_gatherf<16><<<N_EDGES / 4, 256, 0, stream>>>(x0f, nodes_map, E1f);   // E1 = relu(mean x0)
  k_gatherf<8><<<N_NODES / 4, 256, 0, stream>>>(E1f, edges_map, nx1f);   // nx1 = relu(mean E1)
  k_gatherf<16><<<N_EDGES / 4, 256, 0, stream>>>(nx1f, nodes_map, E2f);  // E2 = relu(mean nx1)
  k_gatherf<8><<<N_NODES / 4, 256, 0, stream>>>(E2f, edges_map, nx2f);   // nx2 = relu(mean E2)

  k_head<<<MPAD / 64, 256, 0, stream>>>(x0f, nx1f, nx2f, W1F, b1, W2T, b2, out);
}

// Round 9
// 200.253 us; speedup vs baseline: 1.1995x; 1.1995x over previous
//
#include <hip/hip_runtime.h>
#include <hip/hip_bf16.h>

typedef unsigned int u32;
typedef unsigned short u16;
typedef unsigned char u8;
typedef __attribute__((ext_vector_type(4))) float f32x4;
typedef __attribute__((ext_vector_type(2))) float f32x2;
typedef __attribute__((ext_vector_type(2))) long i64x2;

#define N_NODES 100000
#define N_EDGES 50000
#define D0      128
#define MPAD    100096
#define HIDN    256
#define NC      40

__device__ __forceinline__ u16 f2b(float f) {
  u32 u = __float_as_uint(f);
  u32 r = (u + 0x7fffu + ((u >> 16) & 1u)) >> 16;
  return (u16)r;
}
__device__ __forceinline__ void load_lds16(const void* g, void* l) {
  __builtin_amdgcn_global_load_lds((const __attribute__((address_space(1))) u32*)g,
                                   (__attribute__((address_space(3))) u32*)l, 16, 0, 0);
}
// byte-offset field swap within a 128B row: bits [6:5] <-> [4:3] (involution)
__device__ __forceinline__ int swapf(int o) {
  return ((o >> 2) & 0x18) | ((o << 2) & 0x60) | (o & 7);
}

// ---- fused prep ---------------------------------------------------------
__global__ __launch_bounds__(256) void k_prep(const float* __restrict__ node_x,
                                              const float* __restrict__ W1,
                                              const float* __restrict__ W2,
                                              u8* __restrict__ x0f, u8* __restrict__ nx1f,
                                              u8* __restrict__ nx2f, u8* __restrict__ W1F,
                                              u16* __restrict__ W2T) {
  const int blk = blockIdx.x;
  const int tid = threadIdx.x;
  if (blk < 12500) {
    int t = blk * 256 + tid;                      // one u32 (4 fp8) each
    int row = t >> 5;
    int o = (t & 31) * 4;                         // dest byte offset (perm space)
    int p = swapf(o);                             // src col
    const float4 v = *(const float4*)(node_x + (size_t)row * 128 + p);
    int w = __builtin_amdgcn_cvt_pk_fp8_f32(v.x, v.y, 0, false);
    w = __builtin_amdgcn_cvt_pk_fp8_f32(v.z, v.w, w, true);
    *(u32*)(x0f + (size_t)row * 128 + o) = (u32)w;
  } else if (blk < 12536) {
    int t = (blk - 12500) * 256 + tid;            // 9216 u32 zeros
    const size_t PO = (size_t)N_NODES * 128;
    u32* dst;
    if (t < 3072)      dst = (u32*)(x0f + PO) + t;
    else if (t < 6144) dst = (u32*)(nx1f + PO) + (t - 3072);
    else               dst = (u32*)(nx2f + PO) + (t - 6144);
    *dst = 0;
  } else if (blk < 12792) {
    int n = blk - 12536;
    if (tid < 192) {
      int d0 = 2 * tid;                           // dest k (0..383), even
      int c = d0 >> 7, od = d0 & 127;
      int ks = (c << 7) | swapf(od);              // src k (consecutive pair)
      float v[2];
#pragma unroll
      for (int j = 0; j < 2; ++j) {
        int k = ks + j;
        if (k < 128)      v[j] = W1[k * 256 + n];
        else if (k < 256) v[j] = W1[k * 256 + n] + W1[(k + 128) * 256 + n];
        else              v[j] = W1[(k + 128) * 256 + n];
      }
      int w = __builtin_amdgcn_cvt_pk_fp8_f32(v[0] * 64.f, v[1] * 64.f, 0, false);
      *(u16*)(W1F + (size_t)n * 384 + d0) = (u16)w;
    }
  } else {
    int t = (blk - 12792) * 256 + tid;            // 48*256
    int n = t >> 8, k = t & 255;
    W2T[t] = (n < NC) ? f2b(W2[k * NC + n]) : (u16)0;
  }
}

// ---- gather / segment-mean: 32 rows per wave, S segments ----------------
// u32 per lane, 32 lanes per row, 2 rows per load instruction.
// Half-wave h covers rows j = i + 16h of the wave's 32-row list; with
// D*(S/2) = 16, each half-wave's rows are exactly S/2 whole segments ->
// no cross-lane reduction at all. Map indices are contiguous (w*32..w*32+31)
// and wave-uniform -> s_load_dwordx16 x2; 16 outstanding load instrs
// (32 lines) per wave for latency hiding.
template<int D, int S>
__global__ __launch_bounds__(256) void k_gather2(const u8* __restrict__ src,
                                                 const int* __restrict__ map,
                                                 u8* __restrict__ dst) {
  static_assert(D * S == 32, "wave handles 32 rows");
  const int w = (blockIdx.x * 256 + threadIdx.x) >> 6;
  const int lane = threadIdx.x & 63;
  const int h = lane >> 5, l = lane & 31;
  const int base = __builtin_amdgcn_readfirstlane(w * 32);
  const int* mp = map + base;                     // wave-uniform
  constexpr int SH = S / 2;                       // segments per half-wave
  float acc[SH][4];
#pragma unroll
  for (int k = 0; k < SH; ++k)
#pragma unroll
    for (int c = 0; c < 4; ++c) acc[k][c] = 0.f;
#pragma unroll
  for (int i = 0; i < 16; ++i) {
    int j0 = mp[i];                               // scalar
    int j1 = mp[i + 16];                          // scalar
    int idx = h ? j1 : j0;
    u32 v = *(const u32*)(src + (size_t)idx * 128 + l * 4);
    f32x2 lo = __builtin_amdgcn_cvt_pk_f32_fp8((int)v, false);
    f32x2 hi = __builtin_amdgcn_cvt_pk_f32_fp8((int)v, true);
    acc[i / D][0] += lo[0]; acc[i / D][1] += lo[1];
    acc[i / D][2] += hi[0]; acc[i / D][3] += hi[1];
  }
  const float s = 1.f / D;
  const int segbase = w * S + h * SH;
#pragma unroll
  for (int k = 0; k < SH; ++k) {
    int pk = __builtin_amdgcn_cvt_pk_fp8_f32(fmaxf(acc[k][0] * s, 0.f),
                                             fmaxf(acc[k][1] * s, 0.f), 0, false);
    pk = __builtin_amdgcn_cvt_pk_fp8_f32(fmaxf(acc[k][2] * s, 0.f),
                                         fmaxf(acc[k][3] * s, 0.f), pk, true);
    *(u32*)(dst + (size_t)(segbase + k) * 128 + l * 4) = (u32)pk;
  }
}

// ---- fused head: [x0|nx1|nx2](100096x384 fp8, perm rows) @ W1F -> relu -> @W2 -> lsm
// Round-7 structure (LDS-staged GEMM1, measured 46us) + extra Hs XOR to kill
// the 4-way Hs-write bank conflict.
__global__ __launch_bounds__(256) void k_head(const u8* __restrict__ x0f,
                                              const u8* __restrict__ nx1f,
                                              const u8* __restrict__ nx2f,
                                              const u8* __restrict__ W1F,
                                              const float* __restrict__ b1,
                                              const u16* __restrict__ W2T,
                                              const float* __restrict__ b2,
                                              float* __restrict__ out) {
  __shared__ char lds[40960];
  u8*  As = (u8*)lds;                               // 64 x 128B = 8KB
  u8*  Bs = (u8*)(lds + 8192);                      // 256 x 128B = 32KB
  u16* Hs = (u16*)lds;                              // 64x256 bf16 = 32KB (reuse)
  const int tid = threadIdx.x;
  const int lane = tid & 63;
  const int wid = tid >> 6;
  const int m0 = blockIdx.x * 64;
  const int q = lane >> 4;                          // K quarter

  f32x4 acc[4][4] = {};

#pragma unroll
  for (int ks = 0; ks < 3; ++ks) {
    const u8* Ap = (ks == 0) ? x0f : (ks == 1) ? nx1f : nx2f;
    __syncthreads();
    const int c = tid & 7;
#pragma unroll
    for (int p = 0; p < 2; ++p) {                   // A: 64 rows x 128B
      int row = p * 32 + (tid >> 3);
      load_lds16(Ap + (size_t)(m0 + row) * D0 + ((c ^ (row & 7)) << 4),
                 (char*)As + (p * 256 + tid) * 16);
    }
#pragma unroll
    for (int p = 0; p < 8; ++p) {                   // B: 256 rows x 128B
      int row = p * 32 + (tid >> 3);
      load_lds16(W1F + (size_t)row * 384 + ks * 128 + ((c ^ (row & 7)) << 4),
                 (char*)Bs + (p * 256 + tid) * 16);
    }
    __syncthreads();
#pragma unroll
    for (int h = 0; h < 2; ++h) {                   // kk pair per b128 read
      long a0[4], a1[4], b0[4], b1[4];
#pragma unroll
      for (int m = 0; m < 4; ++m) {
        int r = m * 16 + (lane & 15);
        i64x2 t = *(const i64x2*)(As + r * 128 + ((q * 32 + h * 16) ^ ((r & 7) << 4)));
        a0[m] = t[0]; a1[m] = t[1];
      }
#pragma unroll
      for (int n = 0; n < 4; ++n) {
        int r = wid * 64 + n * 16 + (lane & 15);
        i64x2 t = *(const i64x2*)(Bs + r * 128 + ((q * 32 + h * 16) ^ ((r & 7) << 4)));
        b0[n] = t[0]; b1[n] = t[1];
      }
#pragma unroll
      for (int m = 0; m < 4; ++m)
#pragma unroll
        for (int n = 0; n < 4; ++n) {
          acc[m][n] = __builtin_amdgcn_mfma_f32_16x16x32_fp8_fp8(a0[m], b0[n], acc[m][n], 0, 0, 0);
          acc[m][n] = __builtin_amdgcn_mfma_f32_16x16x32_fp8_fp8(a1[m], b1[n], acc[m][n], 0, 0, 0);
        }
    }
  }

  __syncthreads();                                  // As/Bs dead; reuse as Hs
  const int rb = (lane >> 4) * 4, cb = lane & 15;
#pragma unroll
  for (int n = 0; n < 4; ++n) {                     // H = relu(acc/64 + b1) -> Hs (swizzled)
    int col = wid * 64 + n * 16 + cb;
    float bv = b1[col];
#pragma unroll
    for (int m = 0; m < 4; ++m) {
#pragma unroll
      for (int v = 0; v < 4; ++v) {
        int r = m * 16 + rb + v;
        u32 byo = (((u32)(r << 9) + (u32)(col << 1)) ^ (u32)((r & 7) << 4))
                  ^ (u32)((r & 0x18) << 2);
        *(u16*)((char*)Hs + byo) = f2b(fmaxf(acc[m][n][v] * 0.015625f + bv, 0.f));
      }
    }
  }
  __syncthreads();

  // GEMM2: each wave 16 rows; K=256; N=48 (3 frags); W2 from L2-hot global
  typedef __attribute__((ext_vector_type(8))) short bf16x8;
  f32x4 acc2[3] = {};
  const int r0g = wid * 16;
#pragma unroll
  for (int kk = 0; kk < 8; ++kk) {
    int arow = r0g + (lane & 15);
    int kb = ((kk * 64 + ((lane >> 4) * 16)) ^ ((arow & 7) << 4))
             ^ ((arow & 0x18) << 2);
    bf16x8 a = *(const bf16x8*)((const char*)Hs + arow * 512 + kb);
#pragma unroll
    for (int n = 0; n < 3; ++n) {
      int brow = n * 16 + (lane & 15);
      bf16x8 b = *(const bf16x8*)(W2T + brow * 256 + kk * 32 + (lane >> 4) * 8);
      acc2[n] = __builtin_amdgcn_mfma_f32_16x16x32_bf16(a, b, acc2[n], 0, 0, 0);
    }
  }

  float bias[3];
#pragma unroll
  for (int n = 0; n < 3; ++n) {
    int c2 = n * 16 + cb;
    bias[n] = (c2 < NC) ? b2[c2] : 0.f;
  }
#pragma unroll
  for (int v = 0; v < 4; ++v) {
    float z[3];
    float mx = -1e30f;
#pragma unroll
    for (int n = 0; n < 3; ++n) {
      int c2 = n * 16 + cb;
      z[n] = (c2 < NC) ? (acc2[n][v] + bias[n]) : -1e30f;
      mx = fmaxf(mx, z[n]);
    }
#pragma unroll
    for (int o = 1; o < 16; o <<= 1) mx = fmaxf(mx, __shfl_xor(mx, o));
    float s = 0.f;
#pragma unroll
    for (int n = 0; n < 3; ++n) {
      int c2 = n * 16 + cb;
      if (c2 < NC) s += expf(z[n] - mx);
    }
#pragma unroll
    for (int o = 1; o < 16; o <<= 1) s += __shfl_xor(s, o);
    float lse = logf(s);
    int grow = m0 + r0g + rb + v;
    if (grow < N_NODES) {
#pragma unroll
      for (int n = 0; n < 3; ++n) {
        int c2 = n * 16 + cb;
        if (c2 < NC) out[(size_t)grow * NC + c2] = z[n] - mx - lse;
      }
    }
  }
}

// ---- launch -------------------------------------------------------------

extern "C" void kernel_launch(void* const* d_in, const int* in_sizes, int n_in,
                              void* d_out, int out_size, void* d_ws, size_t ws_size,
                              hipStream_t stream) {
  const float* node_x    = (const float*)d_in[0];
  const int*   nodes_map = (const int*)d_in[1];
  const int*   edges_map = (const int*)d_in[3];
  const float* W1        = (const float*)d_in[5];
  const float* b1        = (const float*)d_in[6];
  const float* W2        = (const float*)d_in[7];
  const float* b2        = (const float*)d_in[8];
  float* out = (float*)d_out;
  char* ws = (char*)d_ws;

  u8*  x0f  = (u8*)(ws + 0);                        // 100096*128 = 12,812,288
  u8*  nx1f = (u8*)(ws + 12812288);
  u8*  nx2f = (u8*)(ws + 25624576);
  u8*  E1f  = (u8*)(ws + 38436864);                 // 50000*128 = 6,400,000
  u8*  E2f  = (u8*)(ws + 44836864);
  u8*  W1F  = (u8*)(ws + 51236864);                 // 256*384
  u16* W2T  = (u16*)(ws + 51335168);                // 48*256*2

  k_prep<<<12840, 256, 0, stream>>>(node_x, W1, W2, x0f, nx1f, nx2f, W1F, W2T);

  // deg16: 50000 segs, 2/wave -> 25000 waves -> 6250 blocks
  // deg8: 100000 segs, 4/wave -> 25000 waves -> 6250 blocks
  k_gather2<16, 2><<<6250, 256, 0, stream>>>(x0f, nodes_map, E1f);   // E1 = relu(mean x0)
  k_gather2<8, 4><<<6250, 256, 0, stream>>>(E1f, edges_map, nx1f);   // nx1 = relu(mean E1)
  k_gather2<16, 2><<<6250, 256, 0, stream>>>(nx1f, nodes_map, E2f);  // E2 = relu(mean nx1)
  k_gather2<8, 4><<<6250, 256, 0, stream>>>(E2f, edges_map, nx2f);   // nx2 = relu(mean E2)

  k_head<<<MPAD / 64, 256, 0, stream>>>(x0f, nx1f, nx2f, W1F, b1, W2T, b2, out);
}